// Round 1
// baseline (503.147 us; speedup 1.0000x reference)
//
#include <hip/hip_runtime.h>
#include <hip/hip_bf16.h>

// ---------------------------------------------------------------------------
// E8 RHT Linear:  y = SU * FHT( FHT(SV * x) @ W^T * Wscale ),  W from codebook
// M=8192 rows of x, K=N_PAD=4096, N=M_PAD=4096 output features.
// All 1/sqrt(4096) FHT normalizations folded into final scale (1/4096).
// ---------------------------------------------------------------------------

using short8 = __attribute__((ext_vector_type(8))) short;
using f32x4  = __attribute__((ext_vector_type(4))) float;

#define AS1 __attribute__((address_space(1)))
#define AS3 __attribute__((address_space(3)))

__device__ __forceinline__ unsigned short f2bf(float f) {
  unsigned int u = __float_as_uint(f);
  unsigned int r = (u + 0x7fffu + ((u >> 16) & 1u)) >> 16;
  return (unsigned short)r;
}

__device__ __forceinline__ void gload16(const void* g, void* l) {
  __builtin_amdgcn_global_load_lds((const AS1 void*)g, (AS3 void*)l, 16, 0, 0);
}

// ---------------------------------------------------------------------------
// Kernel 1: A_rht[row][:] = unnormalized FHT_4096( x[row][:] * SV[:] ) as bf16
// One block per row; 256 threads; elem idx = j*256 + t (16 per thread).
// H_4096 = H_16(j, regs) (x) H_64(lane, shfl) (x) H_4(wave, LDS)
// ---------------------------------------------------------------------------
__global__ __launch_bounds__(256) void rht_in_kernel(const float* __restrict__ X,
                                                     const float* __restrict__ SV,
                                                     unsigned short* __restrict__ A) {
  __shared__ float tmp[4096];
  const int row = blockIdx.x;
  const int t = threadIdx.x;
  const size_t base = (size_t)row * 4096;
  float v[16];
#pragma unroll
  for (int j = 0; j < 16; ++j) {
    int c = j * 256 + t;
    v[j] = X[base + c] * SV[c];
  }
  // H16 over register index j
#pragma unroll
  for (int d = 1; d < 16; d <<= 1) {
#pragma unroll
    for (int j = 0; j < 16; ++j) {
      if ((j & d) == 0) {
        float a = v[j], b = v[j | d];
        v[j] = a + b;
        v[j | d] = a - b;
      }
    }
  }
  // H64 over lane via shfl_xor
  const int lane = t & 63;
#pragma unroll
  for (int d = 1; d < 64; d <<= 1) {
#pragma unroll
    for (int j = 0; j < 16; ++j) {
      float p = __shfl_xor(v[j], d, 64);
      v[j] = (lane & d) ? (p - v[j]) : (v[j] + p);
    }
  }
  // H4 over wave bits (t distances 64, 128) via LDS
#pragma unroll
  for (int dd = 0; dd < 2; ++dd) {
    const int d = 64 << dd;
    if (dd) __syncthreads();
#pragma unroll
    for (int j = 0; j < 16; ++j) tmp[j * 256 + t] = v[j];
    __syncthreads();
#pragma unroll
    for (int j = 0; j < 16; ++j) {
      float p = tmp[j * 256 + (t ^ d)];
      v[j] = (t & d) ? (p - v[j]) : (v[j] + p);
    }
  }
#pragma unroll
  for (int j = 0; j < 16; ++j) {
    A[base + j * 256 + t] = f2bf(v[j]);
  }
}

// ---------------------------------------------------------------------------
// Kernel 2: decode W_rht (4096x4096) from codebook, store bf16 row-major.
// One thread per Qidxs entry (writes 8 contiguous bf16 = 16 B, coalesced).
// ---------------------------------------------------------------------------
__global__ __launch_bounds__(256) void decode_w_kernel(const int* __restrict__ Q,
                                                       const float* __restrict__ cb,
                                                       unsigned short* __restrict__ W) {
  const int e = blockIdx.x * 256 + threadIdx.x;  // 0 .. 4096*512-1
  const int idx = Q[e];
  const float4* c = (const float4*)(cb + (size_t)idx * 8);
  float4 c0 = c[0], c1 = c[1];
  union { short8 v; unsigned short u[8]; } w;
  w.u[0] = f2bf(c0.x); w.u[1] = f2bf(c0.y); w.u[2] = f2bf(c0.z); w.u[3] = f2bf(c0.w);
  w.u[4] = f2bf(c1.x); w.u[5] = f2bf(c1.y); w.u[6] = f2bf(c1.z); w.u[7] = f2bf(c1.w);
  *(short8*)&W[(size_t)e * 8] = w.v;
}

// ---------------------------------------------------------------------------
// Kernel 3: C[8192][4096] (f32) = A[8192][4096](bf16) @ B[4096][4096](bf16)^T
// m97-style: 128x128 tile, BK=32, 4 waves (2x2 of 64x64), 16x16x32 bf16 MFMA,
// global_load_lds width-16 staging, 2 barriers per K-step.
// ---------------------------------------------------------------------------
__global__ __launch_bounds__(256) void gemm_bt_kernel(const unsigned short* __restrict__ A,
                                                      const unsigned short* __restrict__ B,
                                                      float* __restrict__ C) {
  __shared__ unsigned short sA[128 * 32];
  __shared__ unsigned short sB[128 * 32];

  const int bid = blockIdx.x;                 // 2048 blocks (64 x 32 tiles)
  const int swz = (bid & 7) * 256 + (bid >> 3);  // XCD swizzle (2048 % 8 == 0)
  const int tm = swz >> 5;                    // 0..63
  const int tn = swz & 31;                    // 0..31

  const int t = threadIdx.x;
  const int lane = t & 63;
  const int w = t >> 6;
  const int wm = (w >> 1) * 64;
  const int wn = (w & 1) * 64;
  const int fr = lane & 15;
  const int kg = (lane >> 4) * 8;

  // staging coords: thread t covers 8 bf16 at tile (srow, scol), two issues 64 rows apart
  const int srow = t >> 2;         // 0..63
  const int scol = (t & 3) * 8;    // 0,8,16,24

  const unsigned short* Abase = A + (size_t)(tm * 128 + srow) * 4096 + scol;
  const unsigned short* Bbase = B + (size_t)(tn * 128 + srow) * 4096 + scol;
  unsigned short* sAp = &sA[srow * 32 + scol];
  unsigned short* sBp = &sB[srow * 32 + scol];

  f32x4 acc[4][4];
#pragma unroll
  for (int m = 0; m < 4; ++m)
#pragma unroll
    for (int n = 0; n < 4; ++n) {
      f32x4 z = {0.f, 0.f, 0.f, 0.f};
      acc[m][n] = z;
    }

  for (int kt = 0; kt < 128; ++kt) {
    const unsigned short* Ak = Abase + kt * 32;
    const unsigned short* Bk = Bbase + kt * 32;
    gload16(Ak, sAp);
    gload16(Ak + (size_t)64 * 4096, sAp + 64 * 32);
    gload16(Bk, sBp);
    gload16(Bk + (size_t)64 * 4096, sBp + 64 * 32);
    __syncthreads();  // compiler emits vmcnt(0) drain before barrier

    short8 af[4], bf[4];
#pragma unroll
    for (int m = 0; m < 4; ++m)
      af[m] = *(const short8*)&sA[(wm + m * 16 + fr) * 32 + kg];
#pragma unroll
    for (int n = 0; n < 4; ++n)
      bf[n] = *(const short8*)&sB[(wn + n * 16 + fr) * 32 + kg];

#pragma unroll
    for (int m = 0; m < 4; ++m)
#pragma unroll
      for (int n = 0; n < 4; ++n)
        acc[m][n] = __builtin_amdgcn_mfma_f32_16x16x32_bf16(af[m], bf[n], acc[m][n], 0, 0, 0);

    __syncthreads();  // all waves done reading before next overwrite
  }

  // epilogue: C/D layout col = lane&15, row = (lane>>4)*4 + j
  const int crow0 = tm * 128 + wm + (lane >> 4) * 4;
  const int ccol0 = tn * 128 + wn + fr;
#pragma unroll
  for (int m = 0; m < 4; ++m)
#pragma unroll
    for (int n = 0; n < 4; ++n)
#pragma unroll
      for (int j = 0; j < 4; ++j)
        C[(size_t)(crow0 + m * 16 + j) * 4096 + (ccol0 + n * 16)] = acc[m][n][j];
}

// ---------------------------------------------------------------------------
// Kernel 4: in-place FHT_4096 on each row of Y, then * SU * Wscale / 4096.
// ---------------------------------------------------------------------------
__global__ __launch_bounds__(256) void rht_out_kernel(float* __restrict__ Y,
                                                      const float* __restrict__ SU,
                                                      const float* __restrict__ Wscale) {
  __shared__ float tmp[4096];
  const int row = blockIdx.x;
  const int t = threadIdx.x;
  const size_t base = (size_t)row * 4096;
  float v[16];
#pragma unroll
  for (int j = 0; j < 16; ++j) v[j] = Y[base + j * 256 + t];
#pragma unroll
  for (int d = 1; d < 16; d <<= 1) {
#pragma unroll
    for (int j = 0; j < 16; ++j) {
      if ((j & d) == 0) {
        float a = v[j], b = v[j | d];
        v[j] = a + b;
        v[j | d] = a - b;
      }
    }
  }
  const int lane = t & 63;
#pragma unroll
  for (int d = 1; d < 64; d <<= 1) {
#pragma unroll
    for (int j = 0; j < 16; ++j) {
      float p = __shfl_xor(v[j], d, 64);
      v[j] = (lane & d) ? (p - v[j]) : (v[j] + p);
    }
  }
#pragma unroll
  for (int dd = 0; dd < 2; ++dd) {
    const int d = 64 << dd;
    if (dd) __syncthreads();
#pragma unroll
    for (int j = 0; j < 16; ++j) tmp[j * 256 + t] = v[j];
    __syncthreads();
#pragma unroll
    for (int j = 0; j < 16; ++j) {
      float p = tmp[j * 256 + (t ^ d)];
      v[j] = (t & d) ? (p - v[j]) : (v[j] + p);
    }
  }
  const float ws = Wscale[0] * (1.0f / 4096.0f);
#pragma unroll
  for (int j = 0; j < 16; ++j) {
    int c = j * 256 + t;
    Y[base + c] = v[j] * SU[c] * ws;
  }
}

// ---------------------------------------------------------------------------
extern "C" void kernel_launch(void* const* d_in, const int* in_sizes, int n_in,
                              void* d_out, int out_size, void* d_ws, size_t ws_size,
                              hipStream_t stream) {
  const float* x      = (const float*)d_in[0];   // [4,2048,4096] f32
  const int*   Qidxs  = (const int*)d_in[1];     // [4096,512] i32
  const float* SU     = (const float*)d_in[2];   // [4096]
  const float* SV     = (const float*)d_in[3];   // [4096]
  const float* Wscale = (const float*)d_in[4];   // [1]
  const float* cb     = (const float*)d_in[5];   // [256,8]
  float* out = (float*)d_out;                    // [8192,4096] f32

  unsigned short* Arht = (unsigned short*)d_ws;                          // 64 MB bf16
  unsigned short* W    = (unsigned short*)((char*)d_ws + (size_t)8192 * 4096 * 2);  // 32 MB bf16

  rht_in_kernel<<<8192, 256, 0, stream>>>(x, SV, Arht);
  decode_w_kernel<<<(4096 * 512) / 256, 256, 0, stream>>>(Qidxs, cb, W);
  gemm_bt_kernel<<<2048, 256, 0, stream>>>(Arht, W, out);
  rht_out_kernel<<<8192, 256, 0, stream>>>(out, SU, Wscale);
}

// Round 2
// 369.170 us; speedup vs baseline: 1.3629x; 1.3629x over previous
//
#include <hip/hip_runtime.h>
#include <hip/hip_bf16.h>

// ---------------------------------------------------------------------------
// E8 RHT Linear:  y = SU * FHT( FHT(SV * x) @ W^T * Wscale ),  W from codebook
// M=8192 rows of x, K=4096, N=4096 output features.
// GEMM: 256x256 tile, BK=64, 8 waves, 8-phase counted-vmcnt schedule (T2-T5).
// ---------------------------------------------------------------------------

using short8 = __attribute__((ext_vector_type(8))) short;
using f32x4  = __attribute__((ext_vector_type(4))) float;

#define AS1 __attribute__((address_space(1)))
#define AS3 __attribute__((address_space(3)))

__device__ __forceinline__ unsigned short f2bf(float f) {
  unsigned int u = __float_as_uint(f);
  unsigned int r = (u + 0x7fffu + ((u >> 16) & 1u)) >> 16;
  return (unsigned short)r;
}

__device__ __forceinline__ void gload16(const void* g, void* l) {
  __builtin_amdgcn_global_load_lds((const AS1 void*)g, (AS3 void*)l, 16, 0, 0);
}

#define WAIT_VM4 asm volatile("s_waitcnt vmcnt(4)" ::: "memory")
#define WAIT_VM0 asm volatile("s_waitcnt vmcnt(0)" ::: "memory")

// ---------------------------------------------------------------------------
// Kernel 1: A_rht[row][:] = unnormalized FHT_4096( x[row][:] * SV[:] ) as bf16
// ---------------------------------------------------------------------------
__global__ __launch_bounds__(256) void rht_in_kernel(const float* __restrict__ X,
                                                     const float* __restrict__ SV,
                                                     unsigned short* __restrict__ A) {
  __shared__ float tmp[4096];
  const int row = blockIdx.x;
  const int t = threadIdx.x;
  const size_t base = (size_t)row * 4096;
  float v[16];
#pragma unroll
  for (int j = 0; j < 16; ++j) {
    int c = j * 256 + t;
    v[j] = X[base + c] * SV[c];
  }
#pragma unroll
  for (int d = 1; d < 16; d <<= 1) {
#pragma unroll
    for (int j = 0; j < 16; ++j) {
      if ((j & d) == 0) {
        float a = v[j], b = v[j | d];
        v[j] = a + b;
        v[j | d] = a - b;
      }
    }
  }
  const int lane = t & 63;
#pragma unroll
  for (int d = 1; d < 64; d <<= 1) {
#pragma unroll
    for (int j = 0; j < 16; ++j) {
      float p = __shfl_xor(v[j], d, 64);
      v[j] = (lane & d) ? (p - v[j]) : (v[j] + p);
    }
  }
#pragma unroll
  for (int dd = 0; dd < 2; ++dd) {
    const int d = 64 << dd;
    if (dd) __syncthreads();
#pragma unroll
    for (int j = 0; j < 16; ++j) tmp[j * 256 + t] = v[j];
    __syncthreads();
#pragma unroll
    for (int j = 0; j < 16; ++j) {
      float p = tmp[j * 256 + (t ^ d)];
      v[j] = (t & d) ? (p - v[j]) : (v[j] + p);
    }
  }
#pragma unroll
  for (int j = 0; j < 16; ++j) A[base + j * 256 + t] = f2bf(v[j]);
}

// ---------------------------------------------------------------------------
// Kernel 2: decode W_rht (4096x4096) from codebook, bf16 row-major.
// ---------------------------------------------------------------------------
__global__ __launch_bounds__(256) void decode_w_kernel(const int* __restrict__ Q,
                                                       const float* __restrict__ cb,
                                                       unsigned short* __restrict__ W) {
  const int e = blockIdx.x * 256 + threadIdx.x;
  const int idx = Q[e];
  const float4* c = (const float4*)(cb + (size_t)idx * 8);
  float4 c0 = c[0], c1 = c[1];
  union { short8 v; unsigned short u[8]; } w;
  w.u[0] = f2bf(c0.x); w.u[1] = f2bf(c0.y); w.u[2] = f2bf(c0.z); w.u[3] = f2bf(c0.w);
  w.u[4] = f2bf(c1.x); w.u[5] = f2bf(c1.y); w.u[6] = f2bf(c1.z); w.u[7] = f2bf(c1.w);
  *(short8*)&W[(size_t)e * 8] = w.v;
}

// ---------------------------------------------------------------------------
// Kernel 3: C[8192][4096] f32 = A(bf16) @ B(bf16)^T  — 256^2 8-phase template
// LDS: sA/sB [buf][khalf][256 rows][32 k-elems], 2-bit XOR swizzle on 16B
// chunks within each k-half row (inverse-swizzled global source, rule 21).
// Staging groups per K-tile: (A,k0),(B,k0),(A,k1),(B,k1) — 2 gload_lds each.
// Waits: vmcnt(4) at phases 1 & 3 only (counted, never 0 in steady state).
// ---------------------------------------------------------------------------
#define MFMA1(mi, ni, av, bv) \
  acc[mi][ni] = __builtin_amdgcn_mfma_f32_16x16x32_bf16(av, bv, acc[mi][ni], 0, 0, 0)

#define STAGE_A(BB, H, KTN) do {                                          \
  const unsigned short* gp_ = Ag + (KTN) * 64 + (H) * 32;                 \
  gload16(gp_, (unsigned short*)&sA[BB][H][0][0] + d0);                   \
  gload16(gp_ + (size_t)128 * 4096, (unsigned short*)&sA[BB][H][0][0] + d1); \
} while (0)

#define STAGE_B(BB, H, KTN) do {                                          \
  const unsigned short* gp_ = Bg + (KTN) * 64 + (H) * 32;                 \
  gload16(gp_, (unsigned short*)&sB[BB][H][0][0] + d0);                   \
  gload16(gp_ + (size_t)128 * 4096, (unsigned short*)&sB[BB][H][0][0] + d1); \
} while (0)

#define PH(BC, KS, MB, RDB, STG, WT) do {                                 \
  short8 a0_ = *(const short8*)&sA[BC][KS][wm + (MB + 0) * 16 + fr][qc];  \
  short8 a1_ = *(const short8*)&sA[BC][KS][wm + (MB + 1) * 16 + fr][qc];  \
  short8 a2_ = *(const short8*)&sA[BC][KS][wm + (MB + 2) * 16 + fr][qc];  \
  short8 a3_ = *(const short8*)&sA[BC][KS][wm + (MB + 3) * 16 + fr][qc];  \
  if (RDB) {                                                              \
    bf0 = *(const short8*)&sB[BC][KS][wn + 0 * 16 + fr][qc];              \
    bf1 = *(const short8*)&sB[BC][KS][wn + 1 * 16 + fr][qc];              \
    bf2 = *(const short8*)&sB[BC][KS][wn + 2 * 16 + fr][qc];              \
    bf3 = *(const short8*)&sB[BC][KS][wn + 3 * 16 + fr][qc];              \
  }                                                                       \
  STG;                                                                    \
  __builtin_amdgcn_s_barrier();                                           \
  asm volatile("s_waitcnt lgkmcnt(0)" ::: "memory");                      \
  __builtin_amdgcn_sched_barrier(0);                                      \
  __builtin_amdgcn_s_setprio(1);                                          \
  MFMA1(MB + 0, 0, a0_, bf0); MFMA1(MB + 0, 1, a0_, bf1);                 \
  MFMA1(MB + 0, 2, a0_, bf2); MFMA1(MB + 0, 3, a0_, bf3);                 \
  MFMA1(MB + 1, 0, a1_, bf0); MFMA1(MB + 1, 1, a1_, bf1);                 \
  MFMA1(MB + 1, 2, a1_, bf2); MFMA1(MB + 1, 3, a1_, bf3);                 \
  MFMA1(MB + 2, 0, a2_, bf0); MFMA1(MB + 2, 1, a2_, bf1);                 \
  MFMA1(MB + 2, 2, a2_, bf2); MFMA1(MB + 2, 3, a2_, bf3);                 \
  MFMA1(MB + 3, 0, a3_, bf0); MFMA1(MB + 3, 1, a3_, bf1);                 \
  MFMA1(MB + 3, 2, a3_, bf2); MFMA1(MB + 3, 3, a3_, bf3);                 \
  __builtin_amdgcn_s_setprio(0);                                          \
  WT;                                                                     \
  __builtin_amdgcn_s_barrier();                                           \
} while (0)

#define TILE(BC, BN_, KTN, DS) do {                                       \
  PH(BC, 0, 0, 1, { if (DS) { STAGE_A(BN_, 0, KTN); } }, {});             \
  PH(BC, 0, 4, 0, { if (DS) { STAGE_B(BN_, 0, KTN); } },                  \
     { if ((KTN) < 64) { WAIT_VM4; } else { WAIT_VM0; } });               \
  PH(BC, 1, 0, 1, { if (DS) { STAGE_A(BN_, 1, KTN); } }, {});             \
  PH(BC, 1, 4, 0, { if (DS) { STAGE_B(BN_, 1, KTN); } },                  \
     { if ((KTN) < 64) { WAIT_VM4; } });                                  \
} while (0)

__global__ __launch_bounds__(512, 2) void gemm_bt_kernel(const unsigned short* __restrict__ A,
                                                         const unsigned short* __restrict__ B,
                                                         float* __restrict__ C) {
  __shared__ unsigned short sA[2][2][256][32];
  __shared__ unsigned short sB[2][2][256][32];

  const int bid = blockIdx.x;                    // 512 blocks = 32 tm x 16 tn
  const int swz = (bid & 7) * 64 + (bid >> 3);   // XCD swizzle (512 % 8 == 0)
  const int tm = swz >> 4;                       // 0..31
  const int tn = swz & 15;                       // 0..15

  const int t = threadIdx.x;
  const int lane = t & 63;
  const int w = t >> 6;
  const int wm = (w >> 2) * 128;                 // wave M offset (2 waves)
  const int wn = (w & 3) * 64;                   // wave N offset (4 waves)
  const int fr = lane & 15;
  const int qc = ((lane >> 4) ^ (lane & 3)) * 8; // swizzled k-chunk (read side)

  // staging: thread t covers LDS row sr (and sr+128), dest chunk t&3;
  // source k-chunk inverse-swizzled so reads with qc see linear data.
  const int sr = t >> 2;                         // 0..127
  const int sc = ((t & 3) ^ ((t >> 2) & 3)) * 8; // source k-chunk within half
  const unsigned short* Ag = A + (size_t)(tm * 256 + sr) * 4096 + sc;
  const unsigned short* Bg = B + (size_t)(tn * 256 + sr) * 4096 + sc;
  const int d0 = t * 8;                          // dest elem offset, load 0
  const int d1 = (512 + t) * 8;                  // dest elem offset, load 1

  f32x4 acc[8][4];
#pragma unroll
  for (int m = 0; m < 8; ++m)
#pragma unroll
    for (int n = 0; n < 4; ++n) {
      f32x4 z = {0.f, 0.f, 0.f, 0.f};
      acc[m][n] = z;
    }
  short8 bf0, bf1, bf2, bf3;

  // prologue: stage tile 0 (4 groups, 8 loads); need groups 0,1 -> vmcnt(4)
  STAGE_A(0, 0, 0); STAGE_B(0, 0, 0); STAGE_A(0, 1, 0); STAGE_B(0, 1, 0);
  WAIT_VM4;
  __builtin_amdgcn_s_barrier();

  for (int k2 = 0; k2 < 32; ++k2) {
    const int ktn0 = 2 * k2 + 1;
    const int ktn1 = 2 * k2 + 2;
    TILE(0, 1, ktn0, 1);
    TILE(1, 0, ktn1, (ktn1 < 64));
  }

  // epilogue: C/D layout col = lane&15, row = (lane>>4)*4 + j
  const size_t crow0 = (size_t)tm * 256 + wm + (lane >> 4) * 4;
  const int ccol0 = tn * 256 + wn + fr;
#pragma unroll
  for (int mf = 0; mf < 8; ++mf)
#pragma unroll
    for (int j = 0; j < 4; ++j) {
      float* Cp = C + (crow0 + mf * 16 + j) * 4096 + ccol0;
#pragma unroll
      for (int nf = 0; nf < 4; ++nf) Cp[nf * 16] = acc[mf][nf][j];
    }
}

// ---------------------------------------------------------------------------
// Kernel 4: in-place FHT_4096 on each row of Y, then * SU * Wscale / 4096.
// ---------------------------------------------------------------------------
__global__ __launch_bounds__(256) void rht_out_kernel(float* __restrict__ Y,
                                                      const float* __restrict__ SU,
                                                      const float* __restrict__ Wscale) {
  __shared__ float tmp[4096];
  const int row = blockIdx.x;
  const int t = threadIdx.x;
  const size_t base = (size_t)row * 4096;
  float v[16];
#pragma unroll
  for (int j = 0; j < 16; ++j) v[j] = Y[base + j * 256 + t];
#pragma unroll
  for (int d = 1; d < 16; d <<= 1) {
#pragma unroll
    for (int j = 0; j < 16; ++j) {
      if ((j & d) == 0) {
        float a = v[j], b = v[j | d];
        v[j] = a + b;
        v[j | d] = a - b;
      }
    }
  }
  const int lane = t & 63;
#pragma unroll
  for (int d = 1; d < 64; d <<= 1) {
#pragma unroll
    for (int j = 0; j < 16; ++j) {
      float p = __shfl_xor(v[j], d, 64);
      v[j] = (lane & d) ? (p - v[j]) : (v[j] + p);
    }
  }
#pragma unroll
  for (int dd = 0; dd < 2; ++dd) {
    const int d = 64 << dd;
    if (dd) __syncthreads();
#pragma unroll
    for (int j = 0; j < 16; ++j) tmp[j * 256 + t] = v[j];
    __syncthreads();
#pragma unroll
    for (int j = 0; j < 16; ++j) {
      float p = tmp[j * 256 + (t ^ d)];
      v[j] = (t & d) ? (p - v[j]) : (v[j] + p);
    }
  }
  const float ws = Wscale[0] * (1.0f / 4096.0f);
#pragma unroll
  for (int j = 0; j < 16; ++j) {
    int c = j * 256 + t;
    Y[base + c] = v[j] * SU[c] * ws;
  }
}

// ---------------------------------------------------------------------------
extern "C" void kernel_launch(void* const* d_in, const int* in_sizes, int n_in,
                              void* d_out, int out_size, void* d_ws, size_t ws_size,
                              hipStream_t stream) {
  const float* x      = (const float*)d_in[0];
  const int*   Qidxs  = (const int*)d_in[1];
  const float* SU     = (const float*)d_in[2];
  const float* SV     = (const float*)d_in[3];
  const float* Wscale = (const float*)d_in[4];
  const float* cb     = (const float*)d_in[5];
  float* out = (float*)d_out;

  unsigned short* Arht = (unsigned short*)d_ws;
  unsigned short* W    = (unsigned short*)((char*)d_ws + (size_t)8192 * 4096 * 2);

  rht_in_kernel<<<8192, 256, 0, stream>>>(x, SV, Arht);
  decode_w_kernel<<<(4096 * 512) / 256, 256, 0, stream>>>(Qidxs, cb, W);
  gemm_bt_kernel<<<512, 512, 0, stream>>>(Arht, W, out);
  rht_out_kernel<<<8192, 256, 0, stream>>>(out, SU, Wscale);
}

// Round 3
// 355.757 us; speedup vs baseline: 1.4143x; 1.0377x over previous
//
#include <hip/hip_runtime.h>
#include <hip/hip_bf16.h>

// ---------------------------------------------------------------------------
// E8 RHT Linear:  y = SU * FHT( FHT(SV * x) @ W^T * Wscale ),  W from codebook
// M=8192 rows of x, K=4096, N=4096 output features.
// GEMM: 256x256 tile, BK=64, 8 waves, 8-phase counted-vmcnt schedule (T2-T5).
// ---------------------------------------------------------------------------

using short8 = __attribute__((ext_vector_type(8))) short;
using f32x4  = __attribute__((ext_vector_type(4))) float;

#define AS1 __attribute__((address_space(1)))
#define AS3 __attribute__((address_space(3)))

__device__ __forceinline__ unsigned short f2bf(float f) {
  unsigned int u = __float_as_uint(f);
  unsigned int r = (u + 0x7fffu + ((u >> 16) & 1u)) >> 16;
  return (unsigned short)r;
}

__device__ __forceinline__ void gload16(const void* g, void* l) {
  __builtin_amdgcn_global_load_lds((const AS1 void*)g, (AS3 void*)l, 16, 0, 0);
}

#define WAIT_VM4 asm volatile("s_waitcnt vmcnt(4)" ::: "memory")
#define WAIT_VM0 asm volatile("s_waitcnt vmcnt(0)" ::: "memory")

// ---------------------------------------------------------------------------
// Kernel 1: A_rht[row][:] = unnormalized FHT_4096( x[row][:] * SV[:] ) as bf16
// ---------------------------------------------------------------------------
__global__ __launch_bounds__(256) void rht_in_kernel(const float* __restrict__ X,
                                                     const float* __restrict__ SV,
                                                     unsigned short* __restrict__ A) {
  __shared__ float tmp[4096];
  const int row = blockIdx.x;
  const int t = threadIdx.x;
  const size_t base = (size_t)row * 4096;
  float v[16];
#pragma unroll
  for (int j = 0; j < 16; ++j) {
    int c = j * 256 + t;
    v[j] = X[base + c] * SV[c];
  }
#pragma unroll
  for (int d = 1; d < 16; d <<= 1) {
#pragma unroll
    for (int j = 0; j < 16; ++j) {
      if ((j & d) == 0) {
        float a = v[j], b = v[j | d];
        v[j] = a + b;
        v[j | d] = a - b;
      }
    }
  }
  const int lane = t & 63;
#pragma unroll
  for (int d = 1; d < 64; d <<= 1) {
#pragma unroll
    for (int j = 0; j < 16; ++j) {
      float p = __shfl_xor(v[j], d, 64);
      v[j] = (lane & d) ? (p - v[j]) : (v[j] + p);
    }
  }
#pragma unroll
  for (int dd = 0; dd < 2; ++dd) {
    const int d = 64 << dd;
    if (dd) __syncthreads();
#pragma unroll
    for (int j = 0; j < 16; ++j) tmp[j * 256 + t] = v[j];
    __syncthreads();
#pragma unroll
    for (int j = 0; j < 16; ++j) {
      float p = tmp[j * 256 + (t ^ d)];
      v[j] = (t & d) ? (p - v[j]) : (v[j] + p);
    }
  }
#pragma unroll
  for (int j = 0; j < 16; ++j) A[base + j * 256 + t] = f2bf(v[j]);
}

// ---------------------------------------------------------------------------
// Kernel 2: decode W_rht (4096x4096) from codebook, bf16 row-major.
// ---------------------------------------------------------------------------
__global__ __launch_bounds__(256) void decode_w_kernel(const int* __restrict__ Q,
                                                       const float* __restrict__ cb,
                                                       unsigned short* __restrict__ W) {
  const int e = blockIdx.x * 256 + threadIdx.x;
  const int idx = Q[e];
  const float4* c = (const float4*)(cb + (size_t)idx * 8);
  float4 c0 = c[0], c1 = c[1];
  union { short8 v; unsigned short u[8]; } w;
  w.u[0] = f2bf(c0.x); w.u[1] = f2bf(c0.y); w.u[2] = f2bf(c0.z); w.u[3] = f2bf(c0.w);
  w.u[4] = f2bf(c1.x); w.u[5] = f2bf(c1.y); w.u[6] = f2bf(c1.z); w.u[7] = f2bf(c1.w);
  *(short8*)&W[(size_t)e * 8] = w.v;
}

// ---------------------------------------------------------------------------
// Kernel 3: C[8192][4096] f32 = A(bf16) @ B(bf16)^T  — 256^2 8-phase template
// LDS: sA/sB [buf][khalf][256 rows][32 k-elems]. 16B-chunk XOR swizzle within
// each 64B k-half row: LDS chunk = g ^ ((row>>1)&3) (row bits 1-2 — independent
// of bank-parity bit row&1, so 16 lanes cover all 8 bank-groups, 2-way = free).
// Inverse-swizzled global source, linear gload_lds dest (rule 21).
// Staging groups per K-tile: (A,k0),(B,k0),(A,k1),(B,k1) — 2 gload_lds each.
// Waits: vmcnt(4) at phases 1 & 3 only (counted, never 0 in steady state).
// ---------------------------------------------------------------------------
#define MFMA1(mi, ni, av, bv) \
  acc[mi][ni] = __builtin_amdgcn_mfma_f32_16x16x32_bf16(av, bv, acc[mi][ni], 0, 0, 0)

#define STAGE_A(BB, H, KTN) do {                                          \
  const unsigned short* gp_ = Ag + (KTN) * 64 + (H) * 32;                 \
  gload16(gp_, (unsigned short*)&sA[BB][H][0][0] + d0);                   \
  gload16(gp_ + (size_t)128 * 4096, (unsigned short*)&sA[BB][H][0][0] + d1); \
} while (0)

#define STAGE_B(BB, H, KTN) do {                                          \
  const unsigned short* gp_ = Bg + (KTN) * 64 + (H) * 32;                 \
  gload16(gp_, (unsigned short*)&sB[BB][H][0][0] + d0);                   \
  gload16(gp_ + (size_t)128 * 4096, (unsigned short*)&sB[BB][H][0][0] + d1); \
} while (0)

#define PH(BC, KS, MB, RDB, STG, WT) do {                                 \
  short8 a0_ = *(const short8*)&sA[BC][KS][wm + (MB + 0) * 16 + fr][qc];  \
  short8 a1_ = *(const short8*)&sA[BC][KS][wm + (MB + 1) * 16 + fr][qc];  \
  short8 a2_ = *(const short8*)&sA[BC][KS][wm + (MB + 2) * 16 + fr][qc];  \
  short8 a3_ = *(const short8*)&sA[BC][KS][wm + (MB + 3) * 16 + fr][qc];  \
  if (RDB) {                                                              \
    bf0 = *(const short8*)&sB[BC][KS][wn + 0 * 16 + fr][qc];              \
    bf1 = *(const short8*)&sB[BC][KS][wn + 1 * 16 + fr][qc];              \
    bf2 = *(const short8*)&sB[BC][KS][wn + 2 * 16 + fr][qc];              \
    bf3 = *(const short8*)&sB[BC][KS][wn + 3 * 16 + fr][qc];              \
  }                                                                       \
  STG;                                                                    \
  __builtin_amdgcn_s_barrier();                                           \
  asm volatile("s_waitcnt lgkmcnt(0)" ::: "memory");                      \
  __builtin_amdgcn_sched_barrier(0);                                      \
  __builtin_amdgcn_s_setprio(1);                                          \
  MFMA1(MB + 0, 0, a0_, bf0); MFMA1(MB + 0, 1, a0_, bf1);                 \
  MFMA1(MB + 0, 2, a0_, bf2); MFMA1(MB + 0, 3, a0_, bf3);                 \
  MFMA1(MB + 1, 0, a1_, bf0); MFMA1(MB + 1, 1, a1_, bf1);                 \
  MFMA1(MB + 1, 2, a1_, bf2); MFMA1(MB + 1, 3, a1_, bf3);                 \
  MFMA1(MB + 2, 0, a2_, bf0); MFMA1(MB + 2, 1, a2_, bf1);                 \
  MFMA1(MB + 2, 2, a2_, bf2); MFMA1(MB + 2, 3, a2_, bf3);                 \
  MFMA1(MB + 3, 0, a3_, bf0); MFMA1(MB + 3, 1, a3_, bf1);                 \
  MFMA1(MB + 3, 2, a3_, bf2); MFMA1(MB + 3, 3, a3_, bf3);                 \
  __builtin_amdgcn_s_setprio(0);                                          \
  WT;                                                                     \
  __builtin_amdgcn_s_barrier();                                           \
} while (0)

#define TILE(BC, BN_, KTN, DS) do {                                       \
  PH(BC, 0, 0, 1, { if (DS) { STAGE_A(BN_, 0, KTN); } }, {});             \
  PH(BC, 0, 4, 0, { if (DS) { STAGE_B(BN_, 0, KTN); } },                  \
     { if ((KTN) < 64) { WAIT_VM4; } else { WAIT_VM0; } });               \
  PH(BC, 1, 0, 1, { if (DS) { STAGE_A(BN_, 1, KTN); } }, {});             \
  PH(BC, 1, 4, 0, { if (DS) { STAGE_B(BN_, 1, KTN); } },                  \
     { if ((KTN) < 64) { WAIT_VM4; } });                                  \
} while (0)

__global__ __launch_bounds__(512, 2) void gemm_bt_kernel(const unsigned short* __restrict__ A,
                                                         const unsigned short* __restrict__ B,
                                                         float* __restrict__ C) {
  __shared__ unsigned short sA[2][2][256][32];
  __shared__ unsigned short sB[2][2][256][32];

  const int bid = blockIdx.x;                    // 512 blocks = 32 tm x 16 tn
  const int swz = (bid & 7) * 64 + (bid >> 3);   // XCD swizzle (512 % 8 == 0)
  const int tm = swz >> 4;                       // 0..31
  const int tn = swz & 15;                       // 0..15

  const int t = threadIdx.x;
  const int lane = t & 63;
  const int w = t >> 6;
  const int wm = (w >> 2) * 128;                 // wave M offset (2 waves)
  const int wn = (w & 3) * 64;                   // wave N offset (4 waves)
  const int fr = lane & 15;
  // read-side swizzled k-chunk: global chunk g=lane>>4 lives at LDS chunk
  // g ^ ((row>>1)&3); row bits 1-2 == lane bits 1-2 (wm/wn/mb*16 touch bits>=4)
  const int qc = ((lane >> 4) ^ ((lane >> 1) & 3)) * 8;

  // staging: thread t covers LDS row sr=t>>2 (and sr+128), LDS chunk t&3;
  // source global chunk = (t&3) ^ swz(row), swz(row) = (row>>1)&3 = (t>>3)&3.
  const int sr = t >> 2;                         // 0..127
  const int sc = ((t & 3) ^ ((t >> 3) & 3)) * 8; // source k-chunk within half
  const unsigned short* Ag = A + (size_t)(tm * 256 + sr) * 4096 + sc;
  const unsigned short* Bg = B + (size_t)(tn * 256 + sr) * 4096 + sc;
  const int d0 = t * 8;                          // dest elem offset, load 0
  const int d1 = (512 + t) * 8;                  // dest elem offset, load 1

  f32x4 acc[8][4];
#pragma unroll
  for (int m = 0; m < 8; ++m)
#pragma unroll
    for (int n = 0; n < 4; ++n) {
      f32x4 z = {0.f, 0.f, 0.f, 0.f};
      acc[m][n] = z;
    }
  short8 bf0, bf1, bf2, bf3;

  // prologue: stage tile 0 (4 groups, 8 loads); need groups 0,1 -> vmcnt(4)
  STAGE_A(0, 0, 0); STAGE_B(0, 0, 0); STAGE_A(0, 1, 0); STAGE_B(0, 1, 0);
  WAIT_VM4;
  __builtin_amdgcn_s_barrier();

  for (int k2 = 0; k2 < 32; ++k2) {
    const int ktn0 = 2 * k2 + 1;
    const int ktn1 = 2 * k2 + 2;
    TILE(0, 1, ktn0, 1);
    TILE(1, 0, ktn1, (ktn1 < 64));
  }

  // epilogue: C/D layout col = lane&15, row = (lane>>4)*4 + j
  const size_t crow0 = (size_t)tm * 256 + wm + (lane >> 4) * 4;
  const int ccol0 = tn * 256 + wn + fr;
#pragma unroll
  for (int mf = 0; mf < 8; ++mf)
#pragma unroll
    for (int j = 0; j < 4; ++j) {
      float* Cp = C + (crow0 + mf * 16 + j) * 4096 + ccol0;
#pragma unroll
      for (int nf = 0; nf < 4; ++nf) Cp[nf * 16] = acc[mf][nf][j];
    }
}

// ---------------------------------------------------------------------------
// Kernel 4: in-place FHT_4096 on each row of Y, then * SU * Wscale / 4096.
// ---------------------------------------------------------------------------
__global__ __launch_bounds__(256) void rht_out_kernel(float* __restrict__ Y,
                                                      const float* __restrict__ SU,
                                                      const float* __restrict__ Wscale) {
  __shared__ float tmp[4096];
  const int row = blockIdx.x;
  const int t = threadIdx.x;
  const size_t base = (size_t)row * 4096;
  float v[16];
#pragma unroll
  for (int j = 0; j < 16; ++j) v[j] = Y[base + j * 256 + t];
#pragma unroll
  for (int d = 1; d < 16; d <<= 1) {
#pragma unroll
    for (int j = 0; j < 16; ++j) {
      if ((j & d) == 0) {
        float a = v[j], b = v[j | d];
        v[j] = a + b;
        v[j | d] = a - b;
      }
    }
  }
  const int lane = t & 63;
#pragma unroll
  for (int d = 1; d < 64; d <<= 1) {
#pragma unroll
    for (int j = 0; j < 16; ++j) {
      float p = __shfl_xor(v[j], d, 64);
      v[j] = (lane & d) ? (p - v[j]) : (v[j] + p);
    }
  }
#pragma unroll
  for (int dd = 0; dd < 2; ++dd) {
    const int d = 64 << dd;
    if (dd) __syncthreads();
#pragma unroll
    for (int j = 0; j < 16; ++j) tmp[j * 256 + t] = v[j];
    __syncthreads();
#pragma unroll
    for (int j = 0; j < 16; ++j) {
      float p = tmp[j * 256 + (t ^ d)];
      v[j] = (t & d) ? (p - v[j]) : (v[j] + p);
    }
  }
  const float ws = Wscale[0] * (1.0f / 4096.0f);
#pragma unroll
  for (int j = 0; j < 16; ++j) {
    int c = j * 256 + t;
    Y[base + c] = v[j] * SU[c] * ws;
  }
}

// ---------------------------------------------------------------------------
extern "C" void kernel_launch(void* const* d_in, const int* in_sizes, int n_in,
                              void* d_out, int out_size, void* d_ws, size_t ws_size,
                              hipStream_t stream) {
  const float* x      = (const float*)d_in[0];
  const int*   Qidxs  = (const int*)d_in[1];
  const float* SU     = (const float*)d_in[2];
  const float* SV     = (const float*)d_in[3];
  const float* Wscale = (const float*)d_in[4];
  const float* cb     = (const float*)d_in[5];
  float* out = (float*)d_out;

  unsigned short* Arht = (unsigned short*)d_ws;
  unsigned short* W    = (unsigned short*)((char*)d_ws + (size_t)8192 * 4096 * 2);

  rht_in_kernel<<<8192, 256, 0, stream>>>(x, SV, Arht);
  decode_w_kernel<<<(4096 * 512) / 256, 256, 0, stream>>>(Qidxs, cb, W);
  gemm_bt_kernel<<<512, 512, 0, stream>>>(Arht, W, out);
  rht_out_kernel<<<8192, 256, 0, stream>>>(out, SU, Wscale);
}